// Round 20
// baseline (663.675 us; speedup 1.0000x reference)
//
#include <hip/hip_runtime.h>
#include <hip/hip_bf16.h>
#include <hip/hip_fp16.h>

typedef _Float16 half8 __attribute__((ext_vector_type(8)));
typedef float floatx4 __attribute__((ext_vector_type(4)));

union F2H { float f; _Float16 h[2]; };

__device__ __forceinline__ float siluf(float x) {
    return x / (1.0f + __expf(-x));
}

// ---------------- species per node + histogram ----------------
__global__ void k_species(const float* __restrict__ attrs, int* __restrict__ species_o,
                          int* __restrict__ zcount, int N) {
    int n = blockIdx.x * 256 + threadIdx.x;
    if (n >= N) return;
    int z = 0;
    #pragma unroll
    for (int k = 1; k < 10; k++) if (attrs[n * 10 + k] > 0.5f) z = k;
    species_o[n] = z;
    atomicAdd(&zcount[z], 1);
}

// ---- FUSED zperm + weight-prep (r18): wprep depends only on input weights, zperm
// only on zcount -- independent block ranges run CONCURRENTLY in one dispatch.
// Blocks [0, nZp): zperm at 256 threads. Blocks [nZp, ...): wprep at 64 active lanes.
__global__ void k_zpwprep(const int* __restrict__ species_o, const int* __restrict__ zcount,
                          int* __restrict__ zoff, int* __restrict__ perm_n,
                          int* __restrict__ inv_n, int N,
                          const float* __restrict__ RW1, const float* __restrict__ RW2,
                          const float* __restrict__ RW3,
                          const float* __restrict__ Wup_s, const float* __restrict__ Wup_v,
                          const float* __restrict__ Wout_s, const float* __restrict__ Wout_v,
                          const float* __restrict__ Wprod_s, const float* __restrict__ Wprod_v,
                          const float* __restrict__ Wsc_s, const float* __restrict__ Wsc_v,
                          const float* __restrict__ Wemb,
                          _Float16* __restrict__ B1f, _Float16* __restrict__ B2f,
                          _Float16* __restrict__ B3f, _Float16* __restrict__ Bmats,
                          float2* __restrict__ tblup, float2* __restrict__ tblsc,
                          int nZp, int nL52, int nMats) {
    if ((int)blockIdx.x < nZp) {
        // ---- zperm phase ----
        int n = blockIdx.x * 256 + threadIdx.x;
        if (n >= N) return;
        int z = species_o[n];
        int start = 0;
        #pragma unroll
        for (int q = 0; q < 10; q++) {
            if (q == z) break;
            start += (zcount[q] + 15) & ~15;
        }
        int pos = start + atomicAdd(&zoff[z], 1);
        perm_n[pos] = n;
        inv_n[n] = pos;
        return;
    }
    // ---- wprep phase: only first 64 threads of the block active ----
    int lane = threadIdx.x;
    if (lane >= 64) return;
    int wb = (int)blockIdx.x - nZp;
    int quad = lane >> 4, colx = lane & 15;
    if (wb < nL52) {
        int t = wb;
        int layer = t / 52;
        int tt = t % 52;
        if (tt < 4) {
            int nt = tt;
            const float* W = RW1 + (size_t)layer * 512;
            _Float16* dst = B1f + (size_t)layer * 2048 + ((size_t)nt * 64 + lane) * 8;
            #pragma unroll
            for (int j = 0; j < 8; j++) {
                int k = quad * 8 + j, n = nt * 16 + colx;
                dst[j] = (k < 8) ? (_Float16)W[k * 64 + n] : (_Float16)0.0f;
            }
        } else if (tt < 12) {
            int u = tt - 4;
            int kt = u >> 2, nt = u & 3;
            const float* W = RW2 + (size_t)layer * 4096;
            _Float16* dst = B2f + (size_t)layer * 4096 + (((size_t)kt * 4 + nt) * 64 + lane) * 8;
            #pragma unroll
            for (int j = 0; j < 8; j++) {
                int k = kt * 32 + quad * 8 + j, n = nt * 16 + colx;
                dst[j] = (_Float16)W[k * 64 + n];
            }
        } else {
            int u = tt - 12;
            int kt = u / 20, nt = u % 20;
            const float* W = RW3 + (size_t)layer * 20480;
            _Float16* dst = B3f + (size_t)layer * 20480 + (((size_t)kt * 20 + nt) * 64 + lane) * 8;
            const float inv32 = 1.0f / 32.0f;
            const float is3 = 0.5773502691896258f;
            const float is2 = 0.7071067811865476f;
            #pragma unroll
            for (int j = 0; j < 8; j++) {
                int k = kt * 32 + quad * 8 + j, n = nt * 16 + colx;
                int grp = n >> 6;
                float scale = inv32 * (grp == 1 ? is3 : (grp == 4 ? is2 : 1.0f));
                dst[j] = (_Float16)(W[k * 320 + n] * scale);
            }
        }
    } else if (wb < nL52 + nMats) {
        int mid = wb - nL52;
        int layer = mid / 26, m = mid % 26;
        const float* src;
        if (m == 0)      src = Wup_s  + (size_t)layer * 4096;
        else if (m == 1) src = Wup_v  + (size_t)layer * 4096;
        else if (m == 2) src = Wout_s + (size_t)layer * 4096;
        else if (m == 3) src = Wout_v + (size_t)layer * 4096;
        else if (m == 4) src = Wprod_s + (size_t)layer * 4096;
        else if (m == 5) src = Wprod_v + (size_t)layer * 4096;
        else if (m < 16) src = Wsc_s + (size_t)layer * 40960 + (size_t)(m - 6) * 4096;
        else             src = Wsc_v + (size_t)layer * 40960 + (size_t)(m - 16) * 4096;
        _Float16* dst = Bmats + (size_t)mid * 4096;
        for (int t = 0; t < 8; t++) {
            int kt = t >> 2, nt = t & 3;
            #pragma unroll
            for (int j = 0; j < 8; j++) {
                int k = kt * 32 + quad * 8 + j, n = nt * 16 + colx;
                dst[(size_t)t * 512 + lane * 8 + j] = (_Float16)src[k * 64 + n];
            }
        }
    } else {
        // layer-0 species tables: z = wb - nL52 - nMats, ch = lane
        int z = wb - nL52 - nMats;
        const float* wz  = Wemb + (size_t)z * 64;
        const float* wsc = Wsc_s + (size_t)z * 4096;   // layer 0 block, species z
        float accup = 0.0f, accsc = 0.0f;
        for (int k = 0; k < 64; k++) {
            float a = (float)(_Float16)wz[k];
            accup += a * (float)(_Float16)Wup_s[k * 64 + lane];
            accsc += a * (float)(_Float16)wsc[k * 64 + lane];
        }
        F2H u; u.h[0] = (_Float16)accup; u.h[1] = (_Float16)0.0f;
        tblup[z * 64 + lane] = make_float2(u.f, 0.0f);
        F2H w; w.h[0] = (_Float16)accsc; w.h[1] = (_Float16)0.0f;
        tblsc[z * 64 + lane] = make_float2(w.f, 0.0f);
    }
}

// ---- FUSED painit + hist (r17): both depend only on zperm; deg is zeroed by the
// up-front memset (zcount/deg contiguous), so the two phases are race-free and run
// CONCURRENTLY in one dispatch. painit blocks first, hist blocks after.
__global__ void k_paihist(const int* __restrict__ zcount, const int* __restrict__ perm_n,
                          const int* __restrict__ species_o,
                          const float2* __restrict__ tblup, const float2* __restrict__ tblsc,
                          int* __restrict__ species_s, int* __restrict__ origid,
                          float2* __restrict__ packh, float2* __restrict__ scph,
                          float* __restrict__ agg0, float* __restrict__ agg1,
                          const int* __restrict__ ei, const int* __restrict__ inv_n,
                          int* __restrict__ deg, int Npad, int E, int nPa) {
    if ((int)blockIdx.x >= nPa) {
        // hist phase: one thread per edge
        int e = ((int)blockIdx.x - nPa) * 256 + threadIdx.x;
        if (e < E) atomicAdd(&deg[inv_n[ei[E + e]]], 1);
        return;
    }
    // painit phase: layer-0 nodeA eliminated (r16) -- packh/scph from species tables
    int p = blockIdx.x * 4 + (threadIdx.x >> 6);
    if (p >= Npad) return;
    int lane = threadIdx.x & 63;
    int z = -1, run = 0, start = 0, cnt = 0;
    #pragma unroll
    for (int q = 0; q < 10; q++) {
        int c = zcount[q];
        int sz = (c + 15) & ~15;
        if (z < 0 && p < run + sz) { z = q; start = run; cnt = c; }
        run += sz;
    }
    bool pad = (z < 0) || (p >= start + cnt);
    agg0[(size_t)p * 64 + lane] = 0.0f;
    agg1[(size_t)p * 192 + lane] = 0.0f;
    agg1[(size_t)p * 192 + 64 + lane] = 0.0f;
    agg1[(size_t)p * 192 + 128 + lane] = 0.0f;
    if (pad) {
        if (lane == 0) { origid[p] = -1; species_s[p] = (z < 0) ? 9 : z; }
        packh[(size_t)p * 64 + lane] = make_float2(0.0f, 0.0f);
        scph[(size_t)p * 64 + lane]  = make_float2(0.0f, 0.0f);
        return;
    }
    int n = perm_n[p];
    int zn = species_o[n];
    if (lane == 0) { species_s[p] = zn; origid[p] = n; }
    packh[(size_t)p * 64 + lane] = tblup[zn * 64 + lane];
    scph[(size_t)p * 64 + lane]  = tblsc[zn * 64 + lane];
}

// single-block scan over deg -> cursor
__global__ void k_scan(const int* __restrict__ deg, int* __restrict__ cursor, int N) {
    __shared__ int part[1024];
    int t = threadIdx.x;
    int chunk = (N + 1023) / 1024;
    int lo = t * chunk, hi = min(lo + chunk, N);
    int sum = 0;
    for (int i = lo; i < hi; i++) sum += deg[i];
    part[t] = sum;
    __syncthreads();
    for (int off = 1; off < 1024; off <<= 1) {
        int add = (t >= off) ? part[t - off] : 0;
        __syncthreads();
        part[t] += add;
        __syncthreads();
    }
    int run = (t > 0) ? part[t - 1] : 0;
    for (int i = lo; i < hi; i++) { cursor[i] = run; run += deg[i]; }
}

// ---- FUSED edge-permute + geometry: cursor atomic gives sorted position, geometry
// written straight to sorted slot.
__global__ void k_epgeom(const int* __restrict__ ei, const int* __restrict__ inv_n,
                         int* __restrict__ cursor, const float* __restrict__ pos,
                         const float* __restrict__ shifts, float4* __restrict__ geo,
                         _Float16* __restrict__ efh, int* __restrict__ snd_s,
                         int* __restrict__ rcv_s, int E, int Epad, int padnode) {
    int e = blockIdx.x * 256 + threadIdx.x;
    if (e >= Epad) return;
    if (e >= E) {
        // pad edge: real edges fill sorted slots 0..E-1; pads map to slot e directly
        geo[e] = make_float4(0.0f, 0.0f, 0.0f, 0.0f);
        snd_s[e] = padnode;
        rcv_s[e] = padnode;
        half8 z8;
        #pragma unroll
        for (int k = 0; k < 8; k++) z8[k] = (_Float16)0.0f;
        *(half8*)(efh + (size_t)e * 8) = z8;
        return;
    }
    int snd = ei[e], rcv = ei[E + e];
    int rs = inv_n[rcv];
    int j = atomicAdd(&cursor[rs], 1);    // sorted slot for this edge
    float dx = pos[rcv * 3 + 0] - pos[snd * 3 + 0] + shifts[e * 3 + 0];
    float dy = pos[rcv * 3 + 1] - pos[snd * 3 + 1] + shifts[e * 3 + 1];
    float dz = pos[rcv * 3 + 2] - pos[snd * 3 + 2] + shifts[e * 3 + 2];
    float r = sqrtf(dx * dx + dy * dy + dz * dz);
    float rin = 1.0f / (r + 1e-9f);
    const float SQ3 = 1.7320508075688772f;
    geo[j] = make_float4(SQ3 * dx * rin, SQ3 * dy * rin, SQ3 * dz * rin, 0.0f);
    snd_s[j] = inv_n[snd];
    rcv_s[j] = rs;
    float u = r * 0.2f;
    float env = 0.0f;
    if (u < 1.0f) {
        float u2 = u * u;
        float u6 = u2 * u2 * u2;
        env = 1.0f - 28.0f * u6 + 48.0f * u6 * u - 21.0f * u6 * u2;
    }
    const float PIF = 3.14159265358979f;
    float x = PIF * u;
    float sp = __sinf(x), cp = __cosf(x);
    float coef = 0.6324555320336759f * rin * env;
    float sm1 = 0.0f, scur = sp, twoc = 2.0f * cp;
    half8 e8;
    #pragma unroll
    for (int k = 0; k < 8; k++) {
        e8[k] = (_Float16)(coef * scur);
        float nxt = twoc * scur - sm1;
        sm1 = scur; scur = nxt;
    }
    *(half8*)(efh + (size_t)j * 8) = e8;
}

// helper: load A-frag (8 ch of one node) from planar fp32, fp16-convert
__device__ __forceinline__ half8 loadA(const float* __restrict__ base) {
    half8 a;
    float4 f0 = ((const float4*)base)[0];
    float4 f1 = ((const float4*)base)[1];
    a[0]=(_Float16)f0.x; a[1]=(_Float16)f0.y; a[2]=(_Float16)f0.z; a[3]=(_Float16)f0.w;
    a[4]=(_Float16)f1.x; a[5]=(_Float16)f1.y; a[6]=(_Float16)f1.z; a[7]=(_Float16)f1.w;
    return a;
}

#define ROWPB 72

// ---- message kernel r20: r19 barrier-free structure + __launch_bounds__(256, 5).
// LDS 32768 B x 5 = 160 KB = the full per-CU pool; VGPR 60 is far under the
// 5-blocks/CU budget. The old (256,4) bound was the occupancy cap -- lifting it
// adds a 5th resident block per CU (+25% waves) for latency hiding.
#define ROWP 72
#define MROW 64

#define MSG_ROW(R, GR, PRV)                                                    \
    {                                                                          \
        F2H u1_, u2_; u1_.f = PRV.x; u2_.f = PRV.y;                            \
        float pvx = (float)u1_.h[0], pvy = (float)u1_.h[1];                    \
        float pvz = (float)u2_.h[0], pvw = (float)u2_.h[1];                    \
        float w00 = acc0[R], w110 = acc1[R], w011 = acc2[R];                   \
        float w101 = acc3[R], w111 = acc4[R];                                  \
        float dvy = pvy * GR.x + pvz * GR.y + pvw * GR.z;                      \
        float m0v = w00 * pvx + w110 * dvy;                                    \
        float cxv = pvz * GR.z - pvw * GR.y;                                   \
        float cyv = pvw * GR.x - pvy * GR.z;                                   \
        float czv = pvy * GR.y - pvz * GR.x;                                   \
        float wps = w011 * pvx;                                                \
        float m1x = wps * GR.x + w101 * pvy + w111 * cxv;                      \
        float m1y = wps * GR.y + w101 * pvz + w111 * cyv;                      \
        float m1z = wps * GR.z + w101 * pvw + w111 * czv;                      \
        F2H o1_, o2_;                                                          \
        o1_.h[0] = (_Float16)m0v; o1_.h[1] = (_Float16)m1x;                    \
        o2_.h[0] = (_Float16)m1y; o2_.h[1] = (_Float16)m1z;                    \
        mt[(wave * 16 + quad * 4 + R) * MROW + CBc] = make_float2(o1_.f, o2_.f); \
    }

#define MSG_ACC(CB, Q, ACC)                                                    \
    {                                                                          \
        half8 b0_ = *(const half8*)(B3f + (((size_t)(0 * 20 + Q * 4 + CB)) * 64 + lane) * 8); \
        half8 b1_ = *(const half8*)(B3f + (((size_t)(1 * 20 + Q * 4 + CB)) * 64 + lane) * 8); \
        ACC = __builtin_amdgcn_mfma_f32_16x16x32_f16(a3f0, b0_, ACC, 0, 0, 0); \
        ACC = __builtin_amdgcn_mfma_f32_16x16x32_f16(a3f1, b1_, ACC, 0, 0, 0); \
    }

#define MSG_CB(CB)                                                             \
    {                                                                          \
        float2 pv0 = q0[CB * 16], pv1 = q1[CB * 16];                           \
        float2 pv2 = q2[CB * 16], pv3 = q3[CB * 16];                           \
        floatx4 acc0 = {0,0,0,0}, acc1 = {0,0,0,0}, acc2 = {0,0,0,0};          \
        floatx4 acc3 = {0,0,0,0}, acc4 = {0,0,0,0};                            \
        MSG_ACC(CB, 0, acc0) MSG_ACC(CB, 1, acc1) MSG_ACC(CB, 2, acc2)         \
        MSG_ACC(CB, 3, acc3) MSG_ACC(CB, 4, acc4)                              \
        const int CBc = CB * 16 + col;                                         \
        MSG_ROW(0, gr0, pv0) MSG_ROW(1, gr1, pv1)                              \
        MSG_ROW(2, gr2, pv2) MSG_ROW(3, gr3, pv3)                              \
    }

#define RED_STEP(I, RR)                                                        \
    {                                                                          \
        float2 mv = mt[(wave * 16 + I) * MROW + c];                            \
        F2H u1_, u2_; u1_.f = mv.x; u2_.f = mv.y;                              \
        float m0 = (float)u1_.h[0], m1 = (float)u1_.h[1];                      \
        float m2 = (float)u2_.h[0], m3 = (float)u2_.h[1];                      \
        if (RR != prev) {                                                      \
            if (prev >= 0) {                                                   \
                atomicAdd(&agg0[(size_t)prev * 64 + c], a0);                   \
                atomicAdd(&agg1[(size_t)prev * 192 + c], a1);                  \
                atomicAdd(&agg1[(size_t)prev * 192 + 64 + c], a2v);            \
                atomicAdd(&agg1[(size_t)prev * 192 + 128 + c], a3v);           \
            }                                                                  \
            a0 = m0; a1 = m1; a2v = m2; a3v = m3;                              \
            prev = RR;                                                         \
        } else {                                                               \
            a0 += m0; a1 += m1; a2v += m2; a3v += m3;                          \
        }                                                                      \
    }

__global__ __launch_bounds__(256, 5)
void k_msg(const _Float16* __restrict__ efh, const float4* __restrict__ geo,
           const int* __restrict__ snd_s, const int* __restrict__ rcv_s,
           const float2* __restrict__ packh,
           const _Float16* __restrict__ B1f, const _Float16* __restrict__ B2f,
           const _Float16* __restrict__ B3f,
           float* __restrict__ agg0, float* __restrict__ agg1) {
    __shared__ float2 mt[64 * MROW];             // 32768 B; per-wave 8192 B slices
    const int tid = threadIdx.x;
    const int lane = tid & 63;
    const int wave = tid >> 6;
    const int quad = lane >> 4;
    const int col = lane & 15;
    const int j0 = blockIdx.x * 64 + wave * 16;

    // a2/a3 overlay the first 4608 B of this wave's OWN mt slice (rows wave*16..):
    // both dead (a3 in regs) before stage-3 mt writes touch these bytes.
    // No cross-wave aliasing -> no barriers (r19, verified).
    _Float16* slice = (_Float16*)(mt + (size_t)wave * 16 * MROW);
    _Float16* a2w = slice;
    _Float16* a3w = slice + 1152;

    // ---- stage 1: h1 = silu(ef @ RW1) ----
    half8 aef = *(const half8*)(efh + (size_t)(j0 + col) * 8);
    {
        floatx4 c1[4];
        #pragma unroll
        for (int nt = 0; nt < 4; nt++) {
            c1[nt] = (floatx4){0.0f, 0.0f, 0.0f, 0.0f};
            half8 b = *(const half8*)(B1f + ((size_t)nt * 64 + lane) * 8);
            c1[nt] = __builtin_amdgcn_mfma_f32_16x16x32_f16(aef, b, c1[nt], 0, 0, 0);
        }
        #pragma unroll
        for (int nt = 0; nt < 4; nt++)
            #pragma unroll
            for (int r = 0; r < 4; r++)
                a2w[(quad * 4 + r) * ROWP + nt * 16 + col] = (_Float16)siluf(c1[nt][r]);
    }

    // ---- stage 2: h2 = silu(h1 @ RW2) ---- (same-wave ds ordering; no barrier)
    {
        half8 af0 = *(const half8*)&a2w[col * ROWP + quad * 8];
        half8 af1 = *(const half8*)&a2w[col * ROWP + 32 + quad * 8];
        floatx4 c2[4];
        #pragma unroll
        for (int nt = 0; nt < 4; nt++) {
            c2[nt] = (floatx4){0.0f, 0.0f, 0.0f, 0.0f};
            half8 b0 = *(const half8*)(B2f + (((size_t)0 * 4 + nt) * 64 + lane) * 8);
            half8 b1 = *(const half8*)(B2f + (((size_t)1 * 4 + nt) * 64 + lane) * 8);
            c2[nt] = __builtin_amdgcn_mfma_f32_16x16x32_f16(af0, b0, c2[nt], 0, 0, 0);
            c2[nt] = __builtin_amdgcn_mfma_f32_16x16x32_f16(af1, b1, c2[nt], 0, 0, 0);
        }
        #pragma unroll
        for (int nt = 0; nt < 4; nt++)
            #pragma unroll
            for (int r = 0; r < 4; r++)
                a3w[(quad * 4 + r) * ROWP + nt * 16 + col] = (_Float16)siluf(c2[nt][r]);
    }

    half8 a3f0 = *(const half8*)&a3w[col * ROWP + quad * 8];
    half8 a3f1 = *(const half8*)&a3w[col * ROWP + 32 + quad * 8];
    // a3 now in regs; stage-3 mt writes may clobber a2w/a3w bytes (own slice only)

    // per-edge sender/geometry for this lane's 4 quad rows
    const int s0 = snd_s[j0 + quad * 4 + 0];
    const int s1 = snd_s[j0 + quad * 4 + 1];
    const int s2 = snd_s[j0 + quad * 4 + 2];
    const int s3 = snd_s[j0 + quad * 4 + 3];
    const float4 gr0 = geo[j0 + quad * 4 + 0];
    const float4 gr1 = geo[j0 + quad * 4 + 1];
    const float4 gr2 = geo[j0 + quad * 4 + 2];
    const float4 gr3 = geo[j0 + quad * 4 + 3];
    const float2* q0 = packh + (size_t)s0 * 64 + col;
    const float2* q1 = packh + (size_t)s1 * 64 + col;
    const float2* q2 = packh + (size_t)s2 * 64 + col;
    const float2* q3 = packh + (size_t)s3 * 64 + col;

    // pre-issue the 16 rcv_s values into SGPRs (wave-uniform: j0 is per-wave const).
    const int rrv0  = __builtin_amdgcn_readfirstlane(rcv_s[j0 + 0]);
    const int rrv1  = __builtin_amdgcn_readfirstlane(rcv_s[j0 + 1]);
    const int rrv2  = __builtin_amdgcn_readfirstlane(rcv_s[j0 + 2]);
    const int rrv3  = __builtin_amdgcn_readfirstlane(rcv_s[j0 + 3]);
    const int rrv4  = __builtin_amdgcn_readfirstlane(rcv_s[j0 + 4]);
    const int rrv5  = __builtin_amdgcn_readfirstlane(rcv_s[j0 + 5]);
    const int rrv6  = __builtin_amdgcn_readfirstlane(rcv_s[j0 + 6]);
    const int rrv7  = __builtin_amdgcn_readfirstlane(rcv_s[j0 + 7]);
    const int rrv8  = __builtin_amdgcn_readfirstlane(rcv_s[j0 + 8]);
    const int rrv9  = __builtin_amdgcn_readfirstlane(rcv_s[j0 + 9]);
    const int rrv10 = __builtin_amdgcn_readfirstlane(rcv_s[j0 + 10]);
    const int rrv11 = __builtin_amdgcn_readfirstlane(rcv_s[j0 + 11]);
    const int rrv12 = __builtin_amdgcn_readfirstlane(rcv_s[j0 + 12]);
    const int rrv13 = __builtin_amdgcn_readfirstlane(rcv_s[j0 + 13]);
    const int rrv14 = __builtin_amdgcn_readfirstlane(rcv_s[j0 + 14]);
    const int rrv15 = __builtin_amdgcn_readfirstlane(rcv_s[j0 + 15]);
    __builtin_amdgcn_sched_barrier(0);

    // ---- stage 3: w = h2 @ RW3 per 16-ch block; messages -> own mt rows ----
    MSG_CB(0)
    MSG_CB(1)
    MSG_CB(2)
    MSG_CB(3)

    // ---- reduction: thread = (channel, wave-segment); wave-uniform run scan ----
    {
        const int c = lane;
        float a0 = 0.0f, a1 = 0.0f, a2v = 0.0f, a3v = 0.0f;
        int prev = -1;
        RED_STEP(0,  rrv0)  RED_STEP(1,  rrv1)  RED_STEP(2,  rrv2)  RED_STEP(3,  rrv3)
        RED_STEP(4,  rrv4)  RED_STEP(5,  rrv5)  RED_STEP(6,  rrv6)  RED_STEP(7,  rrv7)
        RED_STEP(8,  rrv8)  RED_STEP(9,  rrv9)  RED_STEP(10, rrv10) RED_STEP(11, rrv11)
        RED_STEP(12, rrv12) RED_STEP(13, rrv13) RED_STEP(14, rrv14) RED_STEP(15, rrv15)
        if (prev >= 0) {
            atomicAdd(&agg0[(size_t)prev * 64 + c], a0);
            atomicAdd(&agg1[(size_t)prev * 192 + c], a1);
            atomicAdd(&agg1[(size_t)prev * 192 + 64 + c], a2v);
            atomicAdd(&agg1[(size_t)prev * 192 + 128 + c], a3v);
        }
    }
}

// ---- FUSED node kernel: nodeB(i)+nodeA(i+1), 4 waves/block, LDS-STAGED A (r12) ----
__global__ __launch_bounds__(256, 4)
void k_nodeBA(float* __restrict__ agg0, float* __restrict__ agg1,
              const int* __restrict__ species, const int* __restrict__ origid,
              const _Float16* __restrict__ Bout_s, const _Float16* __restrict__ Bout_v,
              const _Float16* __restrict__ Bprod_s, const _Float16* __restrict__ Bprod_v,
              const float* __restrict__ P0l, const float* __restrict__ P1l,
              const _Float16* __restrict__ Bup_s, const _Float16* __restrict__ Bup_v,
              const _Float16* __restrict__ Bsc_s, const _Float16* __restrict__ Bsc_v,
              float2* __restrict__ scph, float2* __restrict__ packh,
              float* __restrict__ out, int Npad, int layer, int Ltot) {
    __shared__ _Float16 lw[4 * 16 * ROWPB];
    const int tid = threadIdx.x;
    const int lane = tid & 63;
    const int nt = tid >> 6;
    const int quad = lane >> 4, col = lane & 15;
    const int n0 = blockIdx.x * 16;
    if (n0 >= Npad) return;
    const int z = species[n0];
    const int ch = nt * 16 + col;
    const int node = n0 + col;

    // stage: wave nt loads plane nt of agg (0:agg0, 1..3:agg1 components) into LDS
    {
        const float* base = (nt == 0) ? (agg0 + (size_t)node * 64)
                                      : (agg1 + (size_t)node * 192 + (size_t)(nt - 1) * 64);
        #pragma unroll
        for (int kt = 0; kt < 2; kt++) {
            int kb = kt * 32 + quad * 8;
            half8 a = loadA(base + kb);
            *(half8*)&lw[nt * 16 * ROWPB + col * ROWPB + kb] = a;
        }
    }
    __syncthreads();

    // ---- phase 1: frags from LDS; barrier; Wout MFMA (own nt); epilogue -> LDS ----
    {
        half8 as[2], av0[2], av1[2], av2[2];
        #pragma unroll
        for (int kt = 0; kt < 2; kt++) {
            int kb = kt * 32 + quad * 8;
            as[kt]  = *(const half8*)&lw[0 * 16 * ROWPB + col * ROWPB + kb];
            av0[kt] = *(const half8*)&lw[1 * 16 * ROWPB + col * ROWPB + kb];
            av1[kt] = *(const half8*)&lw[2 * 16 * ROWPB + col * ROWPB + kb];
            av2[kt] = *(const half8*)&lw[3 * 16 * ROWPB + col * ROWPB + kb];
        }
        __syncthreads();   // all waves hold A before epilogue overwrites LDS
        floatx4 cs = {0,0,0,0}, c0 = {0,0,0,0}, c1 = {0,0,0,0}, c2 = {0,0,0,0};
        #pragma unroll
        for (int kt = 0; kt < 2; kt++) {
            half8 bs = *(const half8*)(Bout_s + (((size_t)kt * 4 + nt) * 64 + lane) * 8);
            half8 bv = *(const half8*)(Bout_v + (((size_t)kt * 4 + nt) * 64 + lane) * 8);
            cs = __builtin_amdgcn_mfma_f32_16x16x32_f16(as[kt],  bs, cs, 0, 0, 0);
            c0 = __builtin_amdgcn_mfma_f32_16x16x32_f16(av0[kt], bv, c0, 0, 0, 0);
            c1 = __builtin_amdgcn_mfma_f32_16x16x32_f16(av1[kt], bv, c1, 0, 0, 0);
            c2 = __builtin_amdgcn_mfma_f32_16x16x32_f16(av2[kt], bv, c2, 0, 0, 0);
        }
        const float* p = P0l + ((size_t)z * 64 + ch) * 3;
        const float* q = P1l + ((size_t)z * 64 + ch) * 2;
        float p0 = p[0], p1 = p[1], p2 = p[2];
        float q0 = q[0], q1 = q[1];
        #pragma unroll
        for (int r = 0; r < 4; r++) {
            int nl = quad * 4 + r;
            float msv = cs[r];
            float m0 = c0[r], m1 = c1[r], m2 = c2[r];
            float ps = p0 * msv + p1 * msv * msv + p2 * (m0 * m0 + m1 * m1 + m2 * m2);
            float qq = q0 + q1 * msv;
            lw[0 * 16 * ROWPB + nl * ROWPB + ch] = (_Float16)ps;
            lw[1 * 16 * ROWPB + nl * ROWPB + ch] = (_Float16)(qq * m0);
            lw[2 * 16 * ROWPB + nl * ROWPB + ch] = (_Float16)(qq * m1);
            lw[3 * 16 * ROWPB + nl * ROWPB + ch] = (_Float16)(qq * m2);
        }
    }
    __syncthreads();
    // ---- phase 2: frags; barrier; Wprod MFMA (own nt) + skip; out; new s,v -> LDS -
    {
        half8 as[2], av0[2], av1[2], av2[2];
        #pragma unroll
        for (int kt = 0; kt < 2; kt++) {
            int kb = kt * 32 + quad * 8;
            as[kt]  = *(const half8*)&lw[0 * 16 * ROWPB + col * ROWPB + kb];
            av0[kt] = *(const half8*)&lw[1 * 16 * ROWPB + col * ROWPB + kb];
            av1[kt] = *(const half8*)&lw[2 * 16 * ROWPB + col * ROWPB + kb];
            av2[kt] = *(const half8*)&lw[3 * 16 * ROWPB + col * ROWPB + kb];
        }
        __syncthreads();   // all waves hold A before overwrite
        int og[4];
        #pragma unroll
        for (int r = 0; r < 4; r++) og[r] = origid[n0 + quad * 4 + r];
        floatx4 cs = {0,0,0,0}, c0 = {0,0,0,0}, c1 = {0,0,0,0}, c2 = {0,0,0,0};
        #pragma unroll
        for (int kt = 0; kt < 2; kt++) {
            half8 bs = *(const half8*)(Bprod_s + (((size_t)kt * 4 + nt) * 64 + lane) * 8);
            half8 bv = *(const half8*)(Bprod_v + (((size_t)kt * 4 + nt) * 64 + lane) * 8);
            cs = __builtin_amdgcn_mfma_f32_16x16x32_f16(as[kt],  bs, cs, 0, 0, 0);
            c0 = __builtin_amdgcn_mfma_f32_16x16x32_f16(av0[kt], bv, c0, 0, 0, 0);
            c1 = __builtin_amdgcn_mfma_f32_16x16x32_f16(av1[kt], bv, c1, 0, 0, 0);
            c2 = __builtin_amdgcn_mfma_f32_16x16x32_f16(av2[kt], bv, c2, 0, 0, 0);
        }
        #pragma unroll
        for (int r = 0; r < 4; r++) {
            int n = n0 + quad * 4 + r;
            int nl = quad * 4 + r;
            float2 scv = scph[(size_t)n * 64 + ch];
            F2H u1, u2; u1.f = scv.x; u2.f = scv.y;
            float sval = cs[r] + (float)u1.h[0];
            float vx = c0[r] + (float)u1.h[1];
            float vy = c1[r] + (float)u2.h[0];
            float vz = c2[r] + (float)u2.h[1];
            if (og[r] >= 0)
                out[(size_t)og[r] * (Ltot * 64) + layer * 64 + ch] = sval;
            lw[0 * 16 * ROWPB + nl * ROWPB + ch] = (_Float16)sval;
            lw[1 * 16 * ROWPB + nl * ROWPB + ch] = (_Float16)vx;
            lw[2 * 16 * ROWPB + nl * ROWPB + ch] = (_Float16)vy;
            lw[3 * 16 * ROWPB + nl * ROWPB + ch] = (_Float16)vz;
        }
    }
    __syncthreads();
    // ---- phase 3: nodeA of layer+1 (own nt), frags from LDS, global writes only ---
    {
        half8 as[2], av0[2], av1[2], av2[2];
        #pragma unroll
        for (int kt = 0; kt < 2; kt++) {
            int kb = kt * 32 + quad * 8;
            as[kt]  = *(const half8*)&lw[0 * 16 * ROWPB + col * ROWPB + kb];
            av0[kt] = *(const half8*)&lw[1 * 16 * ROWPB + col * ROWPB + kb];
            av1[kt] = *(const half8*)&lw[2 * 16 * ROWPB + col * ROWPB + kb];
            av2[kt] = *(const half8*)&lw[3 * 16 * ROWPB + col * ROWPB + kb];
        }
        const _Float16* Bs = Bsc_s + (size_t)z * 4096;
        const _Float16* Bv = Bsc_v + (size_t)z * 4096;
        floatx4 cs = {0,0,0,0}, c0 = {0,0,0,0}, c1 = {0,0,0,0}, c2 = {0,0,0,0};
        floatx4 ds = {0,0,0,0}, d0 = {0,0,0,0}, d1 = {0,0,0,0}, d2 = {0,0,0,0};
        #pragma unroll
        for (int kt = 0; kt < 2; kt++) {
            half8 bs = *(const half8*)(Bup_s + (((size_t)kt * 4 + nt) * 64 + lane) * 8);
            half8 bv = *(const half8*)(Bup_v + (((size_t)kt * 4 + nt) * 64 + lane) * 8);
            half8 es = *(const half8*)(Bs + (((size_t)kt * 4 + nt) * 64 + lane) * 8);
            half8 ev = *(const half8*)(Bv + (((size_t)kt * 4 + nt) * 64 + lane) * 8);
            cs = __builtin_amdgcn_mfma_f32_16x16x32_f16(as[kt],  bs, cs, 0, 0, 0);
            c0 = __builtin_amdgcn_mfma_f32_16x16x32_f16(av0[kt], bv, c0, 0, 0, 0);
            c1 = __builtin_amdgcn_mfma_f32_16x16x32_f16(av1[kt], bv, c1, 0, 0, 0);
            c2 = __builtin_amdgcn_mfma_f32_16x16x32_f16(av2[kt], bv, c2, 0, 0, 0);
            ds = __builtin_amdgcn_mfma_f32_16x16x32_f16(as[kt],  es, ds, 0, 0, 0);
            d0 = __builtin_amdgcn_mfma_f32_16x16x32_f16(av0[kt], ev, d0, 0, 0, 0);
            d1 = __builtin_amdgcn_mfma_f32_16x16x32_f16(av1[kt], ev, d1, 0, 0, 0);
            d2 = __builtin_amdgcn_mfma_f32_16x16x32_f16(av2[kt], ev, d2, 0, 0, 0);
        }
        #pragma unroll
        for (int r = 0; r < 4; r++) {
            int n = n0 + quad * 4 + r;
            F2H u1, u2, w1, w2;
            u1.h[0] = (_Float16)cs[r]; u1.h[1] = (_Float16)c0[r];
            u2.h[0] = (_Float16)c1[r]; u2.h[1] = (_Float16)c2[r];
            w1.h[0] = (_Float16)ds[r]; w1.h[1] = (_Float16)d0[r];
            w2.h[0] = (_Float16)d1[r]; w2.h[1] = (_Float16)d2[r];
            packh[(size_t)n * 64 + ch] = make_float2(u1.f, u2.f);
            scph[(size_t)n * 64 + ch]  = make_float2(w1.f, w2.f);
            agg0[(size_t)n * 64 + ch] = 0.0f;
            agg1[(size_t)n * 192 + ch] = 0.0f;
            agg1[(size_t)n * 192 + 64 + ch] = 0.0f;
            agg1[(size_t)n * 192 + 128 + ch] = 0.0f;
        }
    }
}

// ---- node kernel B (LAST layer only): pruned; 4 waves/block, LDS-staged A (r12) ---
__global__ __launch_bounds__(256, 4)
void k_nodeB(const float* __restrict__ agg0, const float* __restrict__ agg1,
             const int* __restrict__ species, const int* __restrict__ origid,
             const _Float16* __restrict__ Bout_s, const _Float16* __restrict__ Bout_v,
             const _Float16* __restrict__ Bprod_s,
             const float* __restrict__ P0l, const float* __restrict__ P1l,
             const float2* __restrict__ scph, float* __restrict__ out,
             int Npad, int layer, int Ltot) {
    __shared__ _Float16 lw[4 * 16 * ROWPB];
    const int tid = threadIdx.x;
    const int lane = tid & 63;
    const int nt = tid >> 6;
    const int quad = lane >> 4, col = lane & 15;
    const int n0 = blockIdx.x * 16;
    if (n0 >= Npad) return;
    const int z = species[n0];
    const int ch = nt * 16 + col;
    const int node = n0 + col;

    // stage: wave nt loads plane nt of agg into LDS
    {
        const float* base = (nt == 0) ? (agg0 + (size_t)node * 64)
                                      : (agg1 + (size_t)node * 192 + (size_t)(nt - 1) * 64);
        #pragma unroll
        for (int kt = 0; kt < 2; kt++) {
            int kb = kt * 32 + quad * 8;
            half8 a = loadA(base + kb);
            *(half8*)&lw[nt * 16 * ROWPB + col * ROWPB + kb] = a;
        }
    }
    __syncthreads();

    {
        half8 as[2], av0[2], av1[2], av2[2];
        #pragma unroll
        for (int kt = 0; kt < 2; kt++) {
            int kb = kt * 32 + quad * 8;
            as[kt]  = *(const half8*)&lw[0 * 16 * ROWPB + col * ROWPB + kb];
            av0[kt] = *(const half8*)&lw[1 * 16 * ROWPB + col * ROWPB + kb];
            av1[kt] = *(const half8*)&lw[2 * 16 * ROWPB + col * ROWPB + kb];
            av2[kt] = *(const half8*)&lw[3 * 16 * ROWPB + col * ROWPB + kb];
        }
        __syncthreads();   // all waves hold A before ps overwrites plane 0
        floatx4 cs = {0,0,0,0}, c0 = {0,0,0,0}, c1 = {0,0,0,0}, c2 = {0,0,0,0};
        #pragma unroll
        for (int kt = 0; kt < 2; kt++) {
            half8 bs = *(const half8*)(Bout_s + (((size_t)kt * 4 + nt) * 64 + lane) * 8);
            half8 bv = *(const half8*)(Bout_v + (((size_t)kt * 4 + nt) * 64 + lane) * 8);
            cs = __builtin_amdgcn_mfma_f32_16x16x32_f16(as[kt],  bs, cs, 0, 0, 0);
            c0 = __builtin_amdgcn_mfma_f32_16x16x32_f16(av0[kt], bv, c0, 0, 0, 0);
            c1 = __builtin_amdgcn_mfma_f32_16x16x32_f16(av1[kt], bv, c1, 0, 0, 0);
            c2 = __builtin_amdgcn_mfma_f32_16x16x32_f16(av2[kt], bv, c2, 0, 0, 0);
        }
        const float* p = P0l + ((size_t)z * 64 + ch) * 3;
        float p0 = p[0], p1 = p[1], p2 = p[2];
        #pragma unroll
        for (int r = 0; r < 4; r++) {
            int nl = quad * 4 + r;
            float msv = cs[r];
            float m0 = c0[r], m1 = c1[r], m2 = c2[r];
            float ps = p0 * msv + p1 * msv * msv + p2 * (m0 * m0 + m1 * m1 + m2 * m2);
            lw[0 * 16 * ROWPB + nl * ROWPB + ch] = (_Float16)ps;
        }
    }
    __syncthreads();
    {
        half8 as[2];
        #pragma unroll
        for (int kt = 0; kt < 2; kt++) {
            int kb = kt * 32 + quad * 8;
            as[kt] = *(const half8*)&lw[0 * 16 * ROWPB + col * ROWPB + kb];
        }
        int og[4];
        #pragma unroll
        for (int r = 0; r < 4; r++) og[r] = origid[n0 + quad * 4 + r];
        floatx4 cs = {0,0,0,0};
        #pragma unroll
        for (int kt = 0; kt < 2; kt++) {
            half8 bs = *(const half8*)(Bprod_s + (((size_t)kt * 4 + nt) * 64 + lane) * 8);
            cs = __builtin_amdgcn_mfma_f32_16x16x32_f16(as[kt], bs, cs, 0, 0, 0);
        }
        #pragma unroll
        for (int r = 0; r < 4; r++) {
            int n = n0 + quad * 4 + r;
            float2 scv = scph[(size_t)n * 64 + ch];
            F2H u1; u1.f = scv.x;
            float sval = cs[r] + (float)u1.h[0];
            if (og[r] >= 0)
                out[(size_t)og[r] * (Ltot * 64) + layer * 64 + ch] = sval;
        }
    }
}

extern "C" void kernel_launch(void* const* d_in, const int* in_sizes, int n_in,
                              void* d_out, int out_size, void* d_ws, size_t ws_size,
                              hipStream_t stream) {
    const float* node_attrs = (const float*)d_in[0];
    const float* atom_pos   = (const float*)d_in[1];
    const float* shifts     = (const float*)d_in[2];
    const float* W_embed    = (const float*)d_in[3];
    const float* Wup_s      = (const float*)d_in[4];
    const float* Wup_v      = (const float*)d_in[5];
    const float* RW1        = (const float*)d_in[6];
    const float* RW2        = (const float*)d_in[7];
    const float* RW3        = (const float*)d_in[8];
    const float* Wout_s     = (const float*)d_in[9];
    const float* Wout_v     = (const float*)d_in[10];
    const float* Wsc_s      = (const float*)d_in[11];
    const float* Wsc_v      = (const float*)d_in[12];
    const float* P0         = (const float*)d_in[13];
    const float* P1         = (const float*)d_in[14];
    const float* Wprod_s    = (const float*)d_in[15];
    const float* Wprod_v    = (const float*)d_in[16];
    const int*   ei         = (const int*)d_in[17];

    const int N = in_sizes[0] / 10;
    const int E = in_sizes[17] / 2;
    const int L = in_sizes[4] / 4096;
    const int Npad = ((N + 160) + 63) / 64 * 64;   // species-padded, 64-aligned
    const int Epad = (E + 63) / 64 * 64;           // edge-padded to block size
    float* out = (float*)d_out;

    char* wsb = (char*)d_ws;
    size_t off = 0;
    auto alloci = [&](size_t n) {
        int* p = (int*)(wsb + off);
        off = (off + n * 4 + 255) / 256 * 256;
        return p;
    };
    auto allocf = [&](size_t n) {
        float* p = (float*)(wsb + off);
        off = (off + n * 4 + 255) / 256 * 256;
        return p;
    };
    auto alloch = [&](size_t n) {
        _Float16* p = (_Float16*)(wsb + off);
        off = (off + n * 2 + 255) / 256 * 256;
        return p;
    };
    int* species_o = alloci(N);
    int* species_s = alloci(Npad);
    int* zcount    = alloci(64);          // [0..15]=zcount, [16..31]=zoff; 256B block
    int* zoff      = zcount + 16;
    int* deg       = alloci(Npad);        // CONTIGUOUS with zcount: one memset zeroes both
    int* perm_n    = alloci(Npad);
    int* inv_n     = alloci(N);
    int* origid    = alloci(Npad);
    int* cursor    = alloci(Npad);
    int* snd_s     = alloci(Epad);
    int* rcv_s     = alloci(Epad);
    float* agg0  = allocf((size_t)Npad * 64);
    float* agg1  = allocf((size_t)Npad * 192);
    float* geo   = allocf((size_t)Epad * 4);
    _Float16* efh = alloch((size_t)Epad * 8);
    float* packh = allocf((size_t)Npad * 128);
    float* scph  = allocf((size_t)Npad * 128);
    float2* tblup = (float2*)allocf(10 * 64 * 2);
    float2* tblsc = (float2*)allocf(10 * 64 * 2);
    _Float16* B1f   = alloch((size_t)L * 2048);
    _Float16* B2f   = alloch((size_t)L * 4096);
    _Float16* B3f   = alloch((size_t)L * 20480);
    _Float16* Bmats = alloch((size_t)L * 26 * 4096);
    (void)n_in; (void)out_size; (void)ws_size;

    const int NT16 = Npad / 16;
    const int NB = (N + 255) / 256;
    const int EB = (E + 255) / 256;
    const int EPB = (Epad + 255) / 256;
    const int ET64 = Epad / 64;
    const int nPa = (Npad + 3) / 4;
    const int nWprep = 78 * L + 10;

    // one memset covers zcount/zoff (256B block) + deg (contiguous next block)
    hipMemsetAsync(zcount, 0, 256 + (size_t)((Npad * 4 + 255) / 256 * 256), stream);
    k_species<<<NB, 256, 0, stream>>>(node_attrs, species_o, zcount, N);
    // fused zperm + weight-prep: wprep has no pre-chain deps, runs concurrently
    k_zpwprep<<<NB + nWprep, 256, 0, stream>>>(species_o, zcount, zoff, perm_n, inv_n, N,
                                               RW1, RW2, RW3,
                                               Wup_s, Wup_v, Wout_s, Wout_v,
                                               Wprod_s, Wprod_v, Wsc_s, Wsc_v,
                                               W_embed,
                                               B1f, B2f, B3f, Bmats,
                                               tblup, tblsc, NB, 52 * L, 26 * L);
    // fused painit + hist: both depend only on zperm; deg pre-zeroed by memset
    k_paihist<<<nPa + EB, 256, 0, stream>>>(zcount, perm_n, species_o,
                                            tblup, tblsc,
                                            species_s, origid,
                                            (float2*)packh, (float2*)scph,
                                            agg0, agg1,
                                            ei, inv_n, deg, Npad, E, nPa);
    k_scan<<<1, 1024, 0, stream>>>(deg, cursor, Npad);
    k_epgeom<<<EPB, 256, 0, stream>>>(ei, inv_n, cursor, atom_pos, shifts,
                                      (float4*)geo, efh, snd_s, rcv_s, E, Epad, Npad - 1);

    for (int i = 0; i < L; i++) {
        const _Float16* Bl = Bmats + (size_t)i * 26 * 4096;
        k_msg<<<ET64, 256, 0, stream>>>(efh, (const float4*)geo, snd_s, rcv_s,
                                        (const float2*)packh,
                                        B1f + (size_t)i * 2048, B2f + (size_t)i * 4096,
                                        B3f + (size_t)i * 20480, agg0, agg1);
        if (i + 1 < L) {
            const _Float16* Bn = Bmats + (size_t)(i + 1) * 26 * 4096;
            k_nodeBA<<<NT16, 256, 0, stream>>>(agg0, agg1, species_s, origid,
                                               Bl + 2 * 4096, Bl + 3 * 4096,
                                               Bl + 4 * 4096, Bl + 5 * 4096,
                                               P0 + (size_t)i * 1920, P1 + (size_t)i * 1280,
                                               Bn, Bn + 4096,
                                               Bn + 6 * 4096, Bn + 16 * 4096,
                                               (float2*)scph, (float2*)packh,
                                               out, Npad, i, L);
        } else {
            k_nodeB<<<NT16, 256, 0, stream>>>(agg0, agg1, species_s, origid,
                                              Bl + 2 * 4096, Bl + 3 * 4096,
                                              Bl + 4 * 4096,
                                              P0 + (size_t)i * 1920, P1 + (size_t)i * 1280,
                                              (const float2*)scph, out, Npad, i, L);
        }
    }
}

// Round 21
// 513.254 us; speedup vs baseline: 1.2931x; 1.2931x over previous
//
#include <hip/hip_runtime.h>
#include <hip/hip_bf16.h>
#include <hip/hip_fp16.h>

typedef _Float16 half8 __attribute__((ext_vector_type(8)));
typedef float floatx4 __attribute__((ext_vector_type(4)));

union F2H { float f; _Float16 h[2]; };

__device__ __forceinline__ float siluf(float x) {
    return x / (1.0f + __expf(-x));
}

// ---------------- species per node + histogram ----------------
__global__ void k_species(const float* __restrict__ attrs, int* __restrict__ species_o,
                          int* __restrict__ zcount, int N) {
    int n = blockIdx.x * 256 + threadIdx.x;
    if (n >= N) return;
    int z = 0;
    #pragma unroll
    for (int k = 1; k < 10; k++) if (attrs[n * 10 + k] > 0.5f) z = k;
    species_o[n] = z;
    atomicAdd(&zcount[z], 1);
}

// ---- FUSED zperm + weight-prep (r18): wprep depends only on input weights, zperm
// only on zcount -- independent block ranges run CONCURRENTLY in one dispatch.
// Blocks [0, nZp): zperm at 256 threads. Blocks [nZp, ...): wprep at 64 active lanes.
__global__ void k_zpwprep(const int* __restrict__ species_o, const int* __restrict__ zcount,
                          int* __restrict__ zoff, int* __restrict__ perm_n,
                          int* __restrict__ inv_n, int N,
                          const float* __restrict__ RW1, const float* __restrict__ RW2,
                          const float* __restrict__ RW3,
                          const float* __restrict__ Wup_s, const float* __restrict__ Wup_v,
                          const float* __restrict__ Wout_s, const float* __restrict__ Wout_v,
                          const float* __restrict__ Wprod_s, const float* __restrict__ Wprod_v,
                          const float* __restrict__ Wsc_s, const float* __restrict__ Wsc_v,
                          const float* __restrict__ Wemb,
                          _Float16* __restrict__ B1f, _Float16* __restrict__ B2f,
                          _Float16* __restrict__ B3f, _Float16* __restrict__ Bmats,
                          float2* __restrict__ tblup, float2* __restrict__ tblsc,
                          int nZp, int nL52, int nMats) {
    if ((int)blockIdx.x < nZp) {
        // ---- zperm phase ----
        int n = blockIdx.x * 256 + threadIdx.x;
        if (n >= N) return;
        int z = species_o[n];
        int start = 0;
        #pragma unroll
        for (int q = 0; q < 10; q++) {
            if (q == z) break;
            start += (zcount[q] + 15) & ~15;
        }
        int pos = start + atomicAdd(&zoff[z], 1);
        perm_n[pos] = n;
        inv_n[n] = pos;
        return;
    }
    // ---- wprep phase: only first 64 threads of the block active ----
    int lane = threadIdx.x;
    if (lane >= 64) return;
    int wb = (int)blockIdx.x - nZp;
    int quad = lane >> 4, colx = lane & 15;
    if (wb < nL52) {
        int t = wb;
        int layer = t / 52;
        int tt = t % 52;
        if (tt < 4) {
            int nt = tt;
            const float* W = RW1 + (size_t)layer * 512;
            _Float16* dst = B1f + (size_t)layer * 2048 + ((size_t)nt * 64 + lane) * 8;
            #pragma unroll
            for (int j = 0; j < 8; j++) {
                int k = quad * 8 + j, n = nt * 16 + colx;
                dst[j] = (k < 8) ? (_Float16)W[k * 64 + n] : (_Float16)0.0f;
            }
        } else if (tt < 12) {
            int u = tt - 4;
            int kt = u >> 2, nt = u & 3;
            const float* W = RW2 + (size_t)layer * 4096;
            _Float16* dst = B2f + (size_t)layer * 4096 + (((size_t)kt * 4 + nt) * 64 + lane) * 8;
            #pragma unroll
            for (int j = 0; j < 8; j++) {
                int k = kt * 32 + quad * 8 + j, n = nt * 16 + colx;
                dst[j] = (_Float16)W[k * 64 + n];
            }
        } else {
            int u = tt - 12;
            int kt = u / 20, nt = u % 20;
            const float* W = RW3 + (size_t)layer * 20480;
            _Float16* dst = B3f + (size_t)layer * 20480 + (((size_t)kt * 20 + nt) * 64 + lane) * 8;
            const float inv32 = 1.0f / 32.0f;
            const float is3 = 0.5773502691896258f;
            const float is2 = 0.7071067811865476f;
            #pragma unroll
            for (int j = 0; j < 8; j++) {
                int k = kt * 32 + quad * 8 + j, n = nt * 16 + colx;
                int grp = n >> 6;
                float scale = inv32 * (grp == 1 ? is3 : (grp == 4 ? is2 : 1.0f));
                dst[j] = (_Float16)(W[k * 320 + n] * scale);
            }
        }
    } else if (wb < nL52 + nMats) {
        int mid = wb - nL52;
        int layer = mid / 26, m = mid % 26;
        const float* src;
        if (m == 0)      src = Wup_s  + (size_t)layer * 4096;
        else if (m == 1) src = Wup_v  + (size_t)layer * 4096;
        else if (m == 2) src = Wout_s + (size_t)layer * 4096;
        else if (m == 3) src = Wout_v + (size_t)layer * 4096;
        else if (m == 4) src = Wprod_s + (size_t)layer * 4096;
        else if (m == 5) src = Wprod_v + (size_t)layer * 4096;
        else if (m < 16) src = Wsc_s + (size_t)layer * 40960 + (size_t)(m - 6) * 4096;
        else             src = Wsc_v + (size_t)layer * 40960 + (size_t)(m - 16) * 4096;
        _Float16* dst = Bmats + (size_t)mid * 4096;
        for (int t = 0; t < 8; t++) {
            int kt = t >> 2, nt = t & 3;
            #pragma unroll
            for (int j = 0; j < 8; j++) {
                int k = kt * 32 + quad * 8 + j, n = nt * 16 + colx;
                dst[(size_t)t * 512 + lane * 8 + j] = (_Float16)src[k * 64 + n];
            }
        }
    } else {
        // layer-0 species tables: z = wb - nL52 - nMats, ch = lane
        int z = wb - nL52 - nMats;
        const float* wz  = Wemb + (size_t)z * 64;
        const float* wsc = Wsc_s + (size_t)z * 4096;   // layer 0 block, species z
        float accup = 0.0f, accsc = 0.0f;
        for (int k = 0; k < 64; k++) {
            float a = (float)(_Float16)wz[k];
            accup += a * (float)(_Float16)Wup_s[k * 64 + lane];
            accsc += a * (float)(_Float16)wsc[k * 64 + lane];
        }
        F2H u; u.h[0] = (_Float16)accup; u.h[1] = (_Float16)0.0f;
        tblup[z * 64 + lane] = make_float2(u.f, 0.0f);
        F2H w; w.h[0] = (_Float16)accsc; w.h[1] = (_Float16)0.0f;
        tblsc[z * 64 + lane] = make_float2(w.f, 0.0f);
    }
}

// ---- FUSED painit + hist (r17): both depend only on zperm; deg is zeroed by the
// up-front memset (zcount/deg contiguous), so the two phases are race-free and run
// CONCURRENTLY in one dispatch. painit blocks first, hist blocks after.
__global__ void k_paihist(const int* __restrict__ zcount, const int* __restrict__ perm_n,
                          const int* __restrict__ species_o,
                          const float2* __restrict__ tblup, const float2* __restrict__ tblsc,
                          int* __restrict__ species_s, int* __restrict__ origid,
                          float2* __restrict__ packh, float2* __restrict__ scph,
                          float* __restrict__ agg0, float* __restrict__ agg1,
                          const int* __restrict__ ei, const int* __restrict__ inv_n,
                          int* __restrict__ deg, int Npad, int E, int nPa) {
    if ((int)blockIdx.x >= nPa) {
        // hist phase: one thread per edge
        int e = ((int)blockIdx.x - nPa) * 256 + threadIdx.x;
        if (e < E) atomicAdd(&deg[inv_n[ei[E + e]]], 1);
        return;
    }
    // painit phase: layer-0 nodeA eliminated (r16) -- packh/scph from species tables
    int p = blockIdx.x * 4 + (threadIdx.x >> 6);
    if (p >= Npad) return;
    int lane = threadIdx.x & 63;
    int z = -1, run = 0, start = 0, cnt = 0;
    #pragma unroll
    for (int q = 0; q < 10; q++) {
        int c = zcount[q];
        int sz = (c + 15) & ~15;
        if (z < 0 && p < run + sz) { z = q; start = run; cnt = c; }
        run += sz;
    }
    bool pad = (z < 0) || (p >= start + cnt);
    agg0[(size_t)p * 64 + lane] = 0.0f;
    agg1[(size_t)p * 192 + lane] = 0.0f;
    agg1[(size_t)p * 192 + 64 + lane] = 0.0f;
    agg1[(size_t)p * 192 + 128 + lane] = 0.0f;
    if (pad) {
        if (lane == 0) { origid[p] = -1; species_s[p] = (z < 0) ? 9 : z; }
        packh[(size_t)p * 64 + lane] = make_float2(0.0f, 0.0f);
        scph[(size_t)p * 64 + lane]  = make_float2(0.0f, 0.0f);
        return;
    }
    int n = perm_n[p];
    int zn = species_o[n];
    if (lane == 0) { species_s[p] = zn; origid[p] = n; }
    packh[(size_t)p * 64 + lane] = tblup[zn * 64 + lane];
    scph[(size_t)p * 64 + lane]  = tblsc[zn * 64 + lane];
}

// single-block scan over deg -> cursor
__global__ void k_scan(const int* __restrict__ deg, int* __restrict__ cursor, int N) {
    __shared__ int part[1024];
    int t = threadIdx.x;
    int chunk = (N + 1023) / 1024;
    int lo = t * chunk, hi = min(lo + chunk, N);
    int sum = 0;
    for (int i = lo; i < hi; i++) sum += deg[i];
    part[t] = sum;
    __syncthreads();
    for (int off = 1; off < 1024; off <<= 1) {
        int add = (t >= off) ? part[t - off] : 0;
        __syncthreads();
        part[t] += add;
        __syncthreads();
    }
    int run = (t > 0) ? part[t - 1] : 0;
    for (int i = lo; i < hi; i++) { cursor[i] = run; run += deg[i]; }
}

// ---- FUSED edge-permute + geometry: cursor atomic gives sorted position, geometry
// written straight to sorted slot.
__global__ void k_epgeom(const int* __restrict__ ei, const int* __restrict__ inv_n,
                         int* __restrict__ cursor, const float* __restrict__ pos,
                         const float* __restrict__ shifts, float4* __restrict__ geo,
                         _Float16* __restrict__ efh, int* __restrict__ snd_s,
                         int* __restrict__ rcv_s, int E, int Epad, int padnode) {
    int e = blockIdx.x * 256 + threadIdx.x;
    if (e >= Epad) return;
    if (e >= E) {
        // pad edge: real edges fill sorted slots 0..E-1; pads map to slot e directly
        geo[e] = make_float4(0.0f, 0.0f, 0.0f, 0.0f);
        snd_s[e] = padnode;
        rcv_s[e] = padnode;
        half8 z8;
        #pragma unroll
        for (int k = 0; k < 8; k++) z8[k] = (_Float16)0.0f;
        *(half8*)(efh + (size_t)e * 8) = z8;
        return;
    }
    int snd = ei[e], rcv = ei[E + e];
    int rs = inv_n[rcv];
    int j = atomicAdd(&cursor[rs], 1);    // sorted slot for this edge
    float dx = pos[rcv * 3 + 0] - pos[snd * 3 + 0] + shifts[e * 3 + 0];
    float dy = pos[rcv * 3 + 1] - pos[snd * 3 + 1] + shifts[e * 3 + 1];
    float dz = pos[rcv * 3 + 2] - pos[snd * 3 + 2] + shifts[e * 3 + 2];
    float r = sqrtf(dx * dx + dy * dy + dz * dz);
    float rin = 1.0f / (r + 1e-9f);
    const float SQ3 = 1.7320508075688772f;
    geo[j] = make_float4(SQ3 * dx * rin, SQ3 * dy * rin, SQ3 * dz * rin, 0.0f);
    snd_s[j] = inv_n[snd];
    rcv_s[j] = rs;
    float u = r * 0.2f;
    float env = 0.0f;
    if (u < 1.0f) {
        float u2 = u * u;
        float u6 = u2 * u2 * u2;
        env = 1.0f - 28.0f * u6 + 48.0f * u6 * u - 21.0f * u6 * u2;
    }
    const float PIF = 3.14159265358979f;
    float x = PIF * u;
    float sp = __sinf(x), cp = __cosf(x);
    float coef = 0.6324555320336759f * rin * env;
    float sm1 = 0.0f, scur = sp, twoc = 2.0f * cp;
    half8 e8;
    #pragma unroll
    for (int k = 0; k < 8; k++) {
        e8[k] = (_Float16)(coef * scur);
        float nxt = twoc * scur - sm1;
        sm1 = scur; scur = nxt;
    }
    *(half8*)(efh + (size_t)j * 8) = e8;
}

// helper: load A-frag (8 ch of one node) from planar fp32, fp16-convert
__device__ __forceinline__ half8 loadA(const float* __restrict__ base) {
    half8 a;
    float4 f0 = ((const float4*)base)[0];
    float4 f1 = ((const float4*)base)[1];
    a[0]=(_Float16)f0.x; a[1]=(_Float16)f0.y; a[2]=(_Float16)f0.z; a[3]=(_Float16)f0.w;
    a[4]=(_Float16)f1.x; a[5]=(_Float16)f1.y; a[6]=(_Float16)f1.z; a[7]=(_Float16)f1.w;
    return a;
}

#define ROWPB 72

// ---- message kernel r19 (REVERTED from r20): barrier-free, (256,4). r20's (256,5)
// forced the allocator to the 48-VGPR tier -> ~80 B/thread scratch spill
// (WRITE 38.7->358.8 MB, k_msg 97->169 us). This kernel's footprint sits just above
// the 48 tier; occupancy pressure triggers catastrophic spill. (256,4) is final.
#define ROWP 72
#define MROW 64

#define MSG_ROW(R, GR, PRV)                                                    \
    {                                                                          \
        F2H u1_, u2_; u1_.f = PRV.x; u2_.f = PRV.y;                            \
        float pvx = (float)u1_.h[0], pvy = (float)u1_.h[1];                    \
        float pvz = (float)u2_.h[0], pvw = (float)u2_.h[1];                    \
        float w00 = acc0[R], w110 = acc1[R], w011 = acc2[R];                   \
        float w101 = acc3[R], w111 = acc4[R];                                  \
        float dvy = pvy * GR.x + pvz * GR.y + pvw * GR.z;                      \
        float m0v = w00 * pvx + w110 * dvy;                                    \
        float cxv = pvz * GR.z - pvw * GR.y;                                   \
        float cyv = pvw * GR.x - pvy * GR.z;                                   \
        float czv = pvy * GR.y - pvz * GR.x;                                   \
        float wps = w011 * pvx;                                                \
        float m1x = wps * GR.x + w101 * pvy + w111 * cxv;                      \
        float m1y = wps * GR.y + w101 * pvz + w111 * cyv;                      \
        float m1z = wps * GR.z + w101 * pvw + w111 * czv;                      \
        F2H o1_, o2_;                                                          \
        o1_.h[0] = (_Float16)m0v; o1_.h[1] = (_Float16)m1x;                    \
        o2_.h[0] = (_Float16)m1y; o2_.h[1] = (_Float16)m1z;                    \
        mt[(wave * 16 + quad * 4 + R) * MROW + CBc] = make_float2(o1_.f, o2_.f); \
    }

#define MSG_ACC(CB, Q, ACC)                                                    \
    {                                                                          \
        half8 b0_ = *(const half8*)(B3f + (((size_t)(0 * 20 + Q * 4 + CB)) * 64 + lane) * 8); \
        half8 b1_ = *(const half8*)(B3f + (((size_t)(1 * 20 + Q * 4 + CB)) * 64 + lane) * 8); \
        ACC = __builtin_amdgcn_mfma_f32_16x16x32_f16(a3f0, b0_, ACC, 0, 0, 0); \
        ACC = __builtin_amdgcn_mfma_f32_16x16x32_f16(a3f1, b1_, ACC, 0, 0, 0); \
    }

#define MSG_CB(CB)                                                             \
    {                                                                          \
        float2 pv0 = q0[CB * 16], pv1 = q1[CB * 16];                           \
        float2 pv2 = q2[CB * 16], pv3 = q3[CB * 16];                           \
        floatx4 acc0 = {0,0,0,0}, acc1 = {0,0,0,0}, acc2 = {0,0,0,0};          \
        floatx4 acc3 = {0,0,0,0}, acc4 = {0,0,0,0};                            \
        MSG_ACC(CB, 0, acc0) MSG_ACC(CB, 1, acc1) MSG_ACC(CB, 2, acc2)         \
        MSG_ACC(CB, 3, acc3) MSG_ACC(CB, 4, acc4)                              \
        const int CBc = CB * 16 + col;                                         \
        MSG_ROW(0, gr0, pv0) MSG_ROW(1, gr1, pv1)                              \
        MSG_ROW(2, gr2, pv2) MSG_ROW(3, gr3, pv3)                              \
    }

#define RED_STEP(I, RR)                                                        \
    {                                                                          \
        float2 mv = mt[(wave * 16 + I) * MROW + c];                            \
        F2H u1_, u2_; u1_.f = mv.x; u2_.f = mv.y;                              \
        float m0 = (float)u1_.h[0], m1 = (float)u1_.h[1];                      \
        float m2 = (float)u2_.h[0], m3 = (float)u2_.h[1];                      \
        if (RR != prev) {                                                      \
            if (prev >= 0) {                                                   \
                atomicAdd(&agg0[(size_t)prev * 64 + c], a0);                   \
                atomicAdd(&agg1[(size_t)prev * 192 + c], a1);                  \
                atomicAdd(&agg1[(size_t)prev * 192 + 64 + c], a2v);            \
                atomicAdd(&agg1[(size_t)prev * 192 + 128 + c], a3v);           \
            }                                                                  \
            a0 = m0; a1 = m1; a2v = m2; a3v = m3;                              \
            prev = RR;                                                         \
        } else {                                                               \
            a0 += m0; a1 += m1; a2v += m2; a3v += m3;                          \
        }                                                                      \
    }

__global__ __launch_bounds__(256, 4)
void k_msg(const _Float16* __restrict__ efh, const float4* __restrict__ geo,
           const int* __restrict__ snd_s, const int* __restrict__ rcv_s,
           const float2* __restrict__ packh,
           const _Float16* __restrict__ B1f, const _Float16* __restrict__ B2f,
           const _Float16* __restrict__ B3f,
           float* __restrict__ agg0, float* __restrict__ agg1) {
    __shared__ float2 mt[64 * MROW];             // 32768 B; per-wave 8192 B slices
    const int tid = threadIdx.x;
    const int lane = tid & 63;
    const int wave = tid >> 6;
    const int quad = lane >> 4;
    const int col = lane & 15;
    const int j0 = blockIdx.x * 64 + wave * 16;

    // a2/a3 overlay the first 4608 B of this wave's OWN mt slice (rows wave*16..):
    // both dead (a3 in regs) before stage-3 mt writes touch these bytes.
    // No cross-wave aliasing -> no barriers (r19, verified).
    _Float16* slice = (_Float16*)(mt + (size_t)wave * 16 * MROW);
    _Float16* a2w = slice;
    _Float16* a3w = slice + 1152;

    // ---- stage 1: h1 = silu(ef @ RW1) ----
    half8 aef = *(const half8*)(efh + (size_t)(j0 + col) * 8);
    {
        floatx4 c1[4];
        #pragma unroll
        for (int nt = 0; nt < 4; nt++) {
            c1[nt] = (floatx4){0.0f, 0.0f, 0.0f, 0.0f};
            half8 b = *(const half8*)(B1f + ((size_t)nt * 64 + lane) * 8);
            c1[nt] = __builtin_amdgcn_mfma_f32_16x16x32_f16(aef, b, c1[nt], 0, 0, 0);
        }
        #pragma unroll
        for (int nt = 0; nt < 4; nt++)
            #pragma unroll
            for (int r = 0; r < 4; r++)
                a2w[(quad * 4 + r) * ROWP + nt * 16 + col] = (_Float16)siluf(c1[nt][r]);
    }

    // ---- stage 2: h2 = silu(h1 @ RW2) ---- (same-wave ds ordering; no barrier)
    {
        half8 af0 = *(const half8*)&a2w[col * ROWP + quad * 8];
        half8 af1 = *(const half8*)&a2w[col * ROWP + 32 + quad * 8];
        floatx4 c2[4];
        #pragma unroll
        for (int nt = 0; nt < 4; nt++) {
            c2[nt] = (floatx4){0.0f, 0.0f, 0.0f, 0.0f};
            half8 b0 = *(const half8*)(B2f + (((size_t)0 * 4 + nt) * 64 + lane) * 8);
            half8 b1 = *(const half8*)(B2f + (((size_t)1 * 4 + nt) * 64 + lane) * 8);
            c2[nt] = __builtin_amdgcn_mfma_f32_16x16x32_f16(af0, b0, c2[nt], 0, 0, 0);
            c2[nt] = __builtin_amdgcn_mfma_f32_16x16x32_f16(af1, b1, c2[nt], 0, 0, 0);
        }
        #pragma unroll
        for (int nt = 0; nt < 4; nt++)
            #pragma unroll
            for (int r = 0; r < 4; r++)
                a3w[(quad * 4 + r) * ROWP + nt * 16 + col] = (_Float16)siluf(c2[nt][r]);
    }

    half8 a3f0 = *(const half8*)&a3w[col * ROWP + quad * 8];
    half8 a3f1 = *(const half8*)&a3w[col * ROWP + 32 + quad * 8];
    // a3 now in regs; stage-3 mt writes may clobber a2w/a3w bytes (own slice only)

    // per-edge sender/geometry for this lane's 4 quad rows
    const int s0 = snd_s[j0 + quad * 4 + 0];
    const int s1 = snd_s[j0 + quad * 4 + 1];
    const int s2 = snd_s[j0 + quad * 4 + 2];
    const int s3 = snd_s[j0 + quad * 4 + 3];
    const float4 gr0 = geo[j0 + quad * 4 + 0];
    const float4 gr1 = geo[j0 + quad * 4 + 1];
    const float4 gr2 = geo[j0 + quad * 4 + 2];
    const float4 gr3 = geo[j0 + quad * 4 + 3];
    const float2* q0 = packh + (size_t)s0 * 64 + col;
    const float2* q1 = packh + (size_t)s1 * 64 + col;
    const float2* q2 = packh + (size_t)s2 * 64 + col;
    const float2* q3 = packh + (size_t)s3 * 64 + col;

    // pre-issue the 16 rcv_s values into SGPRs (wave-uniform: j0 is per-wave const).
    const int rrv0  = __builtin_amdgcn_readfirstlane(rcv_s[j0 + 0]);
    const int rrv1  = __builtin_amdgcn_readfirstlane(rcv_s[j0 + 1]);
    const int rrv2  = __builtin_amdgcn_readfirstlane(rcv_s[j0 + 2]);
    const int rrv3  = __builtin_amdgcn_readfirstlane(rcv_s[j0 + 3]);
    const int rrv4  = __builtin_amdgcn_readfirstlane(rcv_s[j0 + 4]);
    const int rrv5  = __builtin_amdgcn_readfirstlane(rcv_s[j0 + 5]);
    const int rrv6  = __builtin_amdgcn_readfirstlane(rcv_s[j0 + 6]);
    const int rrv7  = __builtin_amdgcn_readfirstlane(rcv_s[j0 + 7]);
    const int rrv8  = __builtin_amdgcn_readfirstlane(rcv_s[j0 + 8]);
    const int rrv9  = __builtin_amdgcn_readfirstlane(rcv_s[j0 + 9]);
    const int rrv10 = __builtin_amdgcn_readfirstlane(rcv_s[j0 + 10]);
    const int rrv11 = __builtin_amdgcn_readfirstlane(rcv_s[j0 + 11]);
    const int rrv12 = __builtin_amdgcn_readfirstlane(rcv_s[j0 + 12]);
    const int rrv13 = __builtin_amdgcn_readfirstlane(rcv_s[j0 + 13]);
    const int rrv14 = __builtin_amdgcn_readfirstlane(rcv_s[j0 + 14]);
    const int rrv15 = __builtin_amdgcn_readfirstlane(rcv_s[j0 + 15]);
    __builtin_amdgcn_sched_barrier(0);

    // ---- stage 3: w = h2 @ RW3 per 16-ch block; messages -> own mt rows ----
    MSG_CB(0)
    MSG_CB(1)
    MSG_CB(2)
    MSG_CB(3)

    // ---- reduction: thread = (channel, wave-segment); wave-uniform run scan ----
    {
        const int c = lane;
        float a0 = 0.0f, a1 = 0.0f, a2v = 0.0f, a3v = 0.0f;
        int prev = -1;
        RED_STEP(0,  rrv0)  RED_STEP(1,  rrv1)  RED_STEP(2,  rrv2)  RED_STEP(3,  rrv3)
        RED_STEP(4,  rrv4)  RED_STEP(5,  rrv5)  RED_STEP(6,  rrv6)  RED_STEP(7,  rrv7)
        RED_STEP(8,  rrv8)  RED_STEP(9,  rrv9)  RED_STEP(10, rrv10) RED_STEP(11, rrv11)
        RED_STEP(12, rrv12) RED_STEP(13, rrv13) RED_STEP(14, rrv14) RED_STEP(15, rrv15)
        if (prev >= 0) {
            atomicAdd(&agg0[(size_t)prev * 64 + c], a0);
            atomicAdd(&agg1[(size_t)prev * 192 + c], a1);
            atomicAdd(&agg1[(size_t)prev * 192 + 64 + c], a2v);
            atomicAdd(&agg1[(size_t)prev * 192 + 128 + c], a3v);
        }
    }
}

// ---- FUSED node kernel: nodeB(i)+nodeA(i+1), 4 waves/block, LDS-STAGED A (r12) ----
__global__ __launch_bounds__(256, 4)
void k_nodeBA(float* __restrict__ agg0, float* __restrict__ agg1,
              const int* __restrict__ species, const int* __restrict__ origid,
              const _Float16* __restrict__ Bout_s, const _Float16* __restrict__ Bout_v,
              const _Float16* __restrict__ Bprod_s, const _Float16* __restrict__ Bprod_v,
              const float* __restrict__ P0l, const float* __restrict__ P1l,
              const _Float16* __restrict__ Bup_s, const _Float16* __restrict__ Bup_v,
              const _Float16* __restrict__ Bsc_s, const _Float16* __restrict__ Bsc_v,
              float2* __restrict__ scph, float2* __restrict__ packh,
              float* __restrict__ out, int Npad, int layer, int Ltot) {
    __shared__ _Float16 lw[4 * 16 * ROWPB];
    const int tid = threadIdx.x;
    const int lane = tid & 63;
    const int nt = tid >> 6;
    const int quad = lane >> 4, col = lane & 15;
    const int n0 = blockIdx.x * 16;
    if (n0 >= Npad) return;
    const int z = species[n0];
    const int ch = nt * 16 + col;
    const int node = n0 + col;

    // stage: wave nt loads plane nt of agg (0:agg0, 1..3:agg1 components) into LDS
    {
        const float* base = (nt == 0) ? (agg0 + (size_t)node * 64)
                                      : (agg1 + (size_t)node * 192 + (size_t)(nt - 1) * 64);
        #pragma unroll
        for (int kt = 0; kt < 2; kt++) {
            int kb = kt * 32 + quad * 8;
            half8 a = loadA(base + kb);
            *(half8*)&lw[nt * 16 * ROWPB + col * ROWPB + kb] = a;
        }
    }
    __syncthreads();

    // ---- phase 1: frags from LDS; barrier; Wout MFMA (own nt); epilogue -> LDS ----
    {
        half8 as[2], av0[2], av1[2], av2[2];
        #pragma unroll
        for (int kt = 0; kt < 2; kt++) {
            int kb = kt * 32 + quad * 8;
            as[kt]  = *(const half8*)&lw[0 * 16 * ROWPB + col * ROWPB + kb];
            av0[kt] = *(const half8*)&lw[1 * 16 * ROWPB + col * ROWPB + kb];
            av1[kt] = *(const half8*)&lw[2 * 16 * ROWPB + col * ROWPB + kb];
            av2[kt] = *(const half8*)&lw[3 * 16 * ROWPB + col * ROWPB + kb];
        }
        __syncthreads();   // all waves hold A before epilogue overwrites LDS
        floatx4 cs = {0,0,0,0}, c0 = {0,0,0,0}, c1 = {0,0,0,0}, c2 = {0,0,0,0};
        #pragma unroll
        for (int kt = 0; kt < 2; kt++) {
            half8 bs = *(const half8*)(Bout_s + (((size_t)kt * 4 + nt) * 64 + lane) * 8);
            half8 bv = *(const half8*)(Bout_v + (((size_t)kt * 4 + nt) * 64 + lane) * 8);
            cs = __builtin_amdgcn_mfma_f32_16x16x32_f16(as[kt],  bs, cs, 0, 0, 0);
            c0 = __builtin_amdgcn_mfma_f32_16x16x32_f16(av0[kt], bv, c0, 0, 0, 0);
            c1 = __builtin_amdgcn_mfma_f32_16x16x32_f16(av1[kt], bv, c1, 0, 0, 0);
            c2 = __builtin_amdgcn_mfma_f32_16x16x32_f16(av2[kt], bv, c2, 0, 0, 0);
        }
        const float* p = P0l + ((size_t)z * 64 + ch) * 3;
        const float* q = P1l + ((size_t)z * 64 + ch) * 2;
        float p0 = p[0], p1 = p[1], p2 = p[2];
        float q0 = q[0], q1 = q[1];
        #pragma unroll
        for (int r = 0; r < 4; r++) {
            int nl = quad * 4 + r;
            float msv = cs[r];
            float m0 = c0[r], m1 = c1[r], m2 = c2[r];
            float ps = p0 * msv + p1 * msv * msv + p2 * (m0 * m0 + m1 * m1 + m2 * m2);
            float qq = q0 + q1 * msv;
            lw[0 * 16 * ROWPB + nl * ROWPB + ch] = (_Float16)ps;
            lw[1 * 16 * ROWPB + nl * ROWPB + ch] = (_Float16)(qq * m0);
            lw[2 * 16 * ROWPB + nl * ROWPB + ch] = (_Float16)(qq * m1);
            lw[3 * 16 * ROWPB + nl * ROWPB + ch] = (_Float16)(qq * m2);
        }
    }
    __syncthreads();
    // ---- phase 2: frags; barrier; Wprod MFMA (own nt) + skip; out; new s,v -> LDS -
    {
        half8 as[2], av0[2], av1[2], av2[2];
        #pragma unroll
        for (int kt = 0; kt < 2; kt++) {
            int kb = kt * 32 + quad * 8;
            as[kt]  = *(const half8*)&lw[0 * 16 * ROWPB + col * ROWPB + kb];
            av0[kt] = *(const half8*)&lw[1 * 16 * ROWPB + col * ROWPB + kb];
            av1[kt] = *(const half8*)&lw[2 * 16 * ROWPB + col * ROWPB + kb];
            av2[kt] = *(const half8*)&lw[3 * 16 * ROWPB + col * ROWPB + kb];
        }
        __syncthreads();   // all waves hold A before overwrite
        int og[4];
        #pragma unroll
        for (int r = 0; r < 4; r++) og[r] = origid[n0 + quad * 4 + r];
        floatx4 cs = {0,0,0,0}, c0 = {0,0,0,0}, c1 = {0,0,0,0}, c2 = {0,0,0,0};
        #pragma unroll
        for (int kt = 0; kt < 2; kt++) {
            half8 bs = *(const half8*)(Bprod_s + (((size_t)kt * 4 + nt) * 64 + lane) * 8);
            half8 bv = *(const half8*)(Bprod_v + (((size_t)kt * 4 + nt) * 64 + lane) * 8);
            cs = __builtin_amdgcn_mfma_f32_16x16x32_f16(as[kt],  bs, cs, 0, 0, 0);
            c0 = __builtin_amdgcn_mfma_f32_16x16x32_f16(av0[kt], bv, c0, 0, 0, 0);
            c1 = __builtin_amdgcn_mfma_f32_16x16x32_f16(av1[kt], bv, c1, 0, 0, 0);
            c2 = __builtin_amdgcn_mfma_f32_16x16x32_f16(av2[kt], bv, c2, 0, 0, 0);
        }
        #pragma unroll
        for (int r = 0; r < 4; r++) {
            int n = n0 + quad * 4 + r;
            int nl = quad * 4 + r;
            float2 scv = scph[(size_t)n * 64 + ch];
            F2H u1, u2; u1.f = scv.x; u2.f = scv.y;
            float sval = cs[r] + (float)u1.h[0];
            float vx = c0[r] + (float)u1.h[1];
            float vy = c1[r] + (float)u2.h[0];
            float vz = c2[r] + (float)u2.h[1];
            if (og[r] >= 0)
                out[(size_t)og[r] * (Ltot * 64) + layer * 64 + ch] = sval;
            lw[0 * 16 * ROWPB + nl * ROWPB + ch] = (_Float16)sval;
            lw[1 * 16 * ROWPB + nl * ROWPB + ch] = (_Float16)vx;
            lw[2 * 16 * ROWPB + nl * ROWPB + ch] = (_Float16)vy;
            lw[3 * 16 * ROWPB + nl * ROWPB + ch] = (_Float16)vz;
        }
    }
    __syncthreads();
    // ---- phase 3: nodeA of layer+1 (own nt), frags from LDS, global writes only ---
    {
        half8 as[2], av0[2], av1[2], av2[2];
        #pragma unroll
        for (int kt = 0; kt < 2; kt++) {
            int kb = kt * 32 + quad * 8;
            as[kt]  = *(const half8*)&lw[0 * 16 * ROWPB + col * ROWPB + kb];
            av0[kt] = *(const half8*)&lw[1 * 16 * ROWPB + col * ROWPB + kb];
            av1[kt] = *(const half8*)&lw[2 * 16 * ROWPB + col * ROWPB + kb];
            av2[kt] = *(const half8*)&lw[3 * 16 * ROWPB + col * ROWPB + kb];
        }
        const _Float16* Bs = Bsc_s + (size_t)z * 4096;
        const _Float16* Bv = Bsc_v + (size_t)z * 4096;
        floatx4 cs = {0,0,0,0}, c0 = {0,0,0,0}, c1 = {0,0,0,0}, c2 = {0,0,0,0};
        floatx4 ds = {0,0,0,0}, d0 = {0,0,0,0}, d1 = {0,0,0,0}, d2 = {0,0,0,0};
        #pragma unroll
        for (int kt = 0; kt < 2; kt++) {
            half8 bs = *(const half8*)(Bup_s + (((size_t)kt * 4 + nt) * 64 + lane) * 8);
            half8 bv = *(const half8*)(Bup_v + (((size_t)kt * 4 + nt) * 64 + lane) * 8);
            half8 es = *(const half8*)(Bs + (((size_t)kt * 4 + nt) * 64 + lane) * 8);
            half8 ev = *(const half8*)(Bv + (((size_t)kt * 4 + nt) * 64 + lane) * 8);
            cs = __builtin_amdgcn_mfma_f32_16x16x32_f16(as[kt],  bs, cs, 0, 0, 0);
            c0 = __builtin_amdgcn_mfma_f32_16x16x32_f16(av0[kt], bv, c0, 0, 0, 0);
            c1 = __builtin_amdgcn_mfma_f32_16x16x32_f16(av1[kt], bv, c1, 0, 0, 0);
            c2 = __builtin_amdgcn_mfma_f32_16x16x32_f16(av2[kt], bv, c2, 0, 0, 0);
            ds = __builtin_amdgcn_mfma_f32_16x16x32_f16(as[kt],  es, ds, 0, 0, 0);
            d0 = __builtin_amdgcn_mfma_f32_16x16x32_f16(av0[kt], ev, d0, 0, 0, 0);
            d1 = __builtin_amdgcn_mfma_f32_16x16x32_f16(av1[kt], ev, d1, 0, 0, 0);
            d2 = __builtin_amdgcn_mfma_f32_16x16x32_f16(av2[kt], ev, d2, 0, 0, 0);
        }
        #pragma unroll
        for (int r = 0; r < 4; r++) {
            int n = n0 + quad * 4 + r;
            F2H u1, u2, w1, w2;
            u1.h[0] = (_Float16)cs[r]; u1.h[1] = (_Float16)c0[r];
            u2.h[0] = (_Float16)c1[r]; u2.h[1] = (_Float16)c2[r];
            w1.h[0] = (_Float16)ds[r]; w1.h[1] = (_Float16)d0[r];
            w2.h[0] = (_Float16)d1[r]; w2.h[1] = (_Float16)d2[r];
            packh[(size_t)n * 64 + ch] = make_float2(u1.f, u2.f);
            scph[(size_t)n * 64 + ch]  = make_float2(w1.f, w2.f);
            agg0[(size_t)n * 64 + ch] = 0.0f;
            agg1[(size_t)n * 192 + ch] = 0.0f;
            agg1[(size_t)n * 192 + 64 + ch] = 0.0f;
            agg1[(size_t)n * 192 + 128 + ch] = 0.0f;
        }
    }
}

// ---- node kernel B (LAST layer only): pruned; 4 waves/block, LDS-staged A (r12) ---
__global__ __launch_bounds__(256, 4)
void k_nodeB(const float* __restrict__ agg0, const float* __restrict__ agg1,
             const int* __restrict__ species, const int* __restrict__ origid,
             const _Float16* __restrict__ Bout_s, const _Float16* __restrict__ Bout_v,
             const _Float16* __restrict__ Bprod_s,
             const float* __restrict__ P0l, const float* __restrict__ P1l,
             const float2* __restrict__ scph, float* __restrict__ out,
             int Npad, int layer, int Ltot) {
    __shared__ _Float16 lw[4 * 16 * ROWPB];
    const int tid = threadIdx.x;
    const int lane = tid & 63;
    const int nt = tid >> 6;
    const int quad = lane >> 4, col = lane & 15;
    const int n0 = blockIdx.x * 16;
    if (n0 >= Npad) return;
    const int z = species[n0];
    const int ch = nt * 16 + col;
    const int node = n0 + col;

    // stage: wave nt loads plane nt of agg into LDS
    {
        const float* base = (nt == 0) ? (agg0 + (size_t)node * 64)
                                      : (agg1 + (size_t)node * 192 + (size_t)(nt - 1) * 64);
        #pragma unroll
        for (int kt = 0; kt < 2; kt++) {
            int kb = kt * 32 + quad * 8;
            half8 a = loadA(base + kb);
            *(half8*)&lw[nt * 16 * ROWPB + col * ROWPB + kb] = a;
        }
    }
    __syncthreads();

    {
        half8 as[2], av0[2], av1[2], av2[2];
        #pragma unroll
        for (int kt = 0; kt < 2; kt++) {
            int kb = kt * 32 + quad * 8;
            as[kt]  = *(const half8*)&lw[0 * 16 * ROWPB + col * ROWPB + kb];
            av0[kt] = *(const half8*)&lw[1 * 16 * ROWPB + col * ROWPB + kb];
            av1[kt] = *(const half8*)&lw[2 * 16 * ROWPB + col * ROWPB + kb];
            av2[kt] = *(const half8*)&lw[3 * 16 * ROWPB + col * ROWPB + kb];
        }
        __syncthreads();   // all waves hold A before ps overwrites plane 0
        floatx4 cs = {0,0,0,0}, c0 = {0,0,0,0}, c1 = {0,0,0,0}, c2 = {0,0,0,0};
        #pragma unroll
        for (int kt = 0; kt < 2; kt++) {
            half8 bs = *(const half8*)(Bout_s + (((size_t)kt * 4 + nt) * 64 + lane) * 8);
            half8 bv = *(const half8*)(Bout_v + (((size_t)kt * 4 + nt) * 64 + lane) * 8);
            cs = __builtin_amdgcn_mfma_f32_16x16x32_f16(as[kt],  bs, cs, 0, 0, 0);
            c0 = __builtin_amdgcn_mfma_f32_16x16x32_f16(av0[kt], bv, c0, 0, 0, 0);
            c1 = __builtin_amdgcn_mfma_f32_16x16x32_f16(av1[kt], bv, c1, 0, 0, 0);
            c2 = __builtin_amdgcn_mfma_f32_16x16x32_f16(av2[kt], bv, c2, 0, 0, 0);
        }
        const float* p = P0l + ((size_t)z * 64 + ch) * 3;
        float p0 = p[0], p1 = p[1], p2 = p[2];
        #pragma unroll
        for (int r = 0; r < 4; r++) {
            int nl = quad * 4 + r;
            float msv = cs[r];
            float m0 = c0[r], m1 = c1[r], m2 = c2[r];
            float ps = p0 * msv + p1 * msv * msv + p2 * (m0 * m0 + m1 * m1 + m2 * m2);
            lw[0 * 16 * ROWPB + nl * ROWPB + ch] = (_Float16)ps;
        }
    }
    __syncthreads();
    {
        half8 as[2];
        #pragma unroll
        for (int kt = 0; kt < 2; kt++) {
            int kb = kt * 32 + quad * 8;
            as[kt] = *(const half8*)&lw[0 * 16 * ROWPB + col * ROWPB + kb];
        }
        int og[4];
        #pragma unroll
        for (int r = 0; r < 4; r++) og[r] = origid[n0 + quad * 4 + r];
        floatx4 cs = {0,0,0,0};
        #pragma unroll
        for (int kt = 0; kt < 2; kt++) {
            half8 bs = *(const half8*)(Bprod_s + (((size_t)kt * 4 + nt) * 64 + lane) * 8);
            cs = __builtin_amdgcn_mfma_f32_16x16x32_f16(as[kt], bs, cs, 0, 0, 0);
        }
        #pragma unroll
        for (int r = 0; r < 4; r++) {
            int n = n0 + quad * 4 + r;
            float2 scv = scph[(size_t)n * 64 + ch];
            F2H u1; u1.f = scv.x;
            float sval = cs[r] + (float)u1.h[0];
            if (og[r] >= 0)
                out[(size_t)og[r] * (Ltot * 64) + layer * 64 + ch] = sval;
        }
    }
}

extern "C" void kernel_launch(void* const* d_in, const int* in_sizes, int n_in,
                              void* d_out, int out_size, void* d_ws, size_t ws_size,
                              hipStream_t stream) {
    const float* node_attrs = (const float*)d_in[0];
    const float* atom_pos   = (const float*)d_in[1];
    const float* shifts     = (const float*)d_in[2];
    const float* W_embed    = (const float*)d_in[3];
    const float* Wup_s      = (const float*)d_in[4];
    const float* Wup_v      = (const float*)d_in[5];
    const float* RW1        = (const float*)d_in[6];
    const float* RW2        = (const float*)d_in[7];
    const float* RW3        = (const float*)d_in[8];
    const float* Wout_s     = (const float*)d_in[9];
    const float* Wout_v     = (const float*)d_in[10];
    const float* Wsc_s      = (const float*)d_in[11];
    const float* Wsc_v      = (const float*)d_in[12];
    const float* P0         = (const float*)d_in[13];
    const float* P1         = (const float*)d_in[14];
    const float* Wprod_s    = (const float*)d_in[15];
    const float* Wprod_v    = (const float*)d_in[16];
    const int*   ei         = (const int*)d_in[17];

    const int N = in_sizes[0] / 10;
    const int E = in_sizes[17] / 2;
    const int L = in_sizes[4] / 4096;
    const int Npad = ((N + 160) + 63) / 64 * 64;   // species-padded, 64-aligned
    const int Epad = (E + 63) / 64 * 64;           // edge-padded to block size
    float* out = (float*)d_out;

    char* wsb = (char*)d_ws;
    size_t off = 0;
    auto alloci = [&](size_t n) {
        int* p = (int*)(wsb + off);
        off = (off + n * 4 + 255) / 256 * 256;
        return p;
    };
    auto allocf = [&](size_t n) {
        float* p = (float*)(wsb + off);
        off = (off + n * 4 + 255) / 256 * 256;
        return p;
    };
    auto alloch = [&](size_t n) {
        _Float16* p = (_Float16*)(wsb + off);
        off = (off + n * 2 + 255) / 256 * 256;
        return p;
    };
    int* species_o = alloci(N);
    int* species_s = alloci(Npad);
    int* zcount    = alloci(64);          // [0..15]=zcount, [16..31]=zoff; 256B block
    int* zoff      = zcount + 16;
    int* deg       = alloci(Npad);        // CONTIGUOUS with zcount: one memset zeroes both
    int* perm_n    = alloci(Npad);
    int* inv_n     = alloci(N);
    int* origid    = alloci(Npad);
    int* cursor    = alloci(Npad);
    int* snd_s     = alloci(Epad);
    int* rcv_s     = alloci(Epad);
    float* agg0  = allocf((size_t)Npad * 64);
    float* agg1  = allocf((size_t)Npad * 192);
    float* geo   = allocf((size_t)Epad * 4);
    _Float16* efh = alloch((size_t)Epad * 8);
    float* packh = allocf((size_t)Npad * 128);
    float* scph  = allocf((size_t)Npad * 128);
    float2* tblup = (float2*)allocf(10 * 64 * 2);
    float2* tblsc = (float2*)allocf(10 * 64 * 2);
    _Float16* B1f   = alloch((size_t)L * 2048);
    _Float16* B2f   = alloch((size_t)L * 4096);
    _Float16* B3f   = alloch((size_t)L * 20480);
    _Float16* Bmats = alloch((size_t)L * 26 * 4096);
    (void)n_in; (void)out_size; (void)ws_size;

    const int NT16 = Npad / 16;
    const int NB = (N + 255) / 256;
    const int EB = (E + 255) / 256;
    const int EPB = (Epad + 255) / 256;
    const int ET64 = Epad / 64;
    const int nPa = (Npad + 3) / 4;
    const int nWprep = 78 * L + 10;

    // one memset covers zcount/zoff (256B block) + deg (contiguous next block)
    hipMemsetAsync(zcount, 0, 256 + (size_t)((Npad * 4 + 255) / 256 * 256), stream);
    k_species<<<NB, 256, 0, stream>>>(node_attrs, species_o, zcount, N);
    // fused zperm + weight-prep: wprep has no pre-chain deps, runs concurrently
    k_zpwprep<<<NB + nWprep, 256, 0, stream>>>(species_o, zcount, zoff, perm_n, inv_n, N,
                                               RW1, RW2, RW3,
                                               Wup_s, Wup_v, Wout_s, Wout_v,
                                               Wprod_s, Wprod_v, Wsc_s, Wsc_v,
                                               W_embed,
                                               B1f, B2f, B3f, Bmats,
                                               tblup, tblsc, NB, 52 * L, 26 * L);
    // fused painit + hist: both depend only on zperm; deg pre-zeroed by memset
    k_paihist<<<nPa + EB, 256, 0, stream>>>(zcount, perm_n, species_o,
                                            tblup, tblsc,
                                            species_s, origid,
                                            (float2*)packh, (float2*)scph,
                                            agg0, agg1,
                                            ei, inv_n, deg, Npad, E, nPa);
    k_scan<<<1, 1024, 0, stream>>>(deg, cursor, Npad);
    k_epgeom<<<EPB, 256, 0, stream>>>(ei, inv_n, cursor, atom_pos, shifts,
                                      (float4*)geo, efh, snd_s, rcv_s, E, Epad, Npad - 1);

    for (int i = 0; i < L; i++) {
        const _Float16* Bl = Bmats + (size_t)i * 26 * 4096;
        k_msg<<<ET64, 256, 0, stream>>>(efh, (const float4*)geo, snd_s, rcv_s,
                                        (const float2*)packh,
                                        B1f + (size_t)i * 2048, B2f + (size_t)i * 4096,
                                        B3f + (size_t)i * 20480, agg0, agg1);
        if (i + 1 < L) {
            const _Float16* Bn = Bmats + (size_t)(i + 1) * 26 * 4096;
            k_nodeBA<<<NT16, 256, 0, stream>>>(agg0, agg1, species_s, origid,
                                               Bl + 2 * 4096, Bl + 3 * 4096,
                                               Bl + 4 * 4096, Bl + 5 * 4096,
                                               P0 + (size_t)i * 1920, P1 + (size_t)i * 1280,
                                               Bn, Bn + 4096,
                                               Bn + 6 * 4096, Bn + 16 * 4096,
                                               (float2*)scph, (float2*)packh,
                                               out, Npad, i, L);
        } else {
            k_nodeB<<<NT16, 256, 0, stream>>>(agg0, agg1, species_s, origid,
                                              Bl + 2 * 4096, Bl + 3 * 4096,
                                              Bl + 4 * 4096,
                                              P0 + (size_t)i * 1920, P1 + (size_t)i * 1280,
                                              (const float2*)scph, out, Npad, i, L);
        }
    }
}